// Round 12
// baseline (117.618 us; speedup 1.0000x reference)
//
#include <hip/hip_runtime.h>
#include <cstdint>
#include <cstddef>

// Problem: B=8, C=64, H=W=32 -> N=8192 nodes, K=9 neighbors, OUT=64.
// Batches: b = [1024b,1024(b+1)) for b<=6, batch 7 = [7168,8190], batch 8 = {8191}.
// Node g <-> (b = g>>10, hw = g&1023); features x[b][c][hw] (node 8191 -> b=7).
//
// R18: chain-latency attack. R13/R16/R17 (three structures, 8-16 waves/CU,
//  DS-heavy to DS-free) all ~56us @ VALUBusy ~35% -> not throughput-bound;
//  per-wave serial chains dominate (tournament shfl chains + L2 load latency).
//  (1) 4-row INTERLEAVED tournament: one butterfly loop carries g0..g3 -> 8
//      independent shfls per level, ~4x ILP on the dominant chain. cand[]
//      dropped; rare rescan REBUILDS keys from acc+sqa (bitwise-identical).
//  (2) GEMM software pipeline: 2-deep register ping-pong (bA/bB, 2ch each);
//      next group's 8 global b128 loads issue before current group's 160 FMAs.
//  Geometry/IO unchanged from R17: 512 blocks x 16 rows, 4 rows/wave, B from
//  global (L2-resident), LDS = A (4KB) + W overlay (33.3KB total).
//  Exactness: ascending-ch fmaf chains for dot and sq on identical bits ->
//  d(n,n)==0 exactly; keys (dist|jj), jj=256q+4*lane+e -> unique, lax.top_k
//  smaller-index tie-break; batch-7 excludes jj=1023; node 8191 singleton.

typedef unsigned long long u64;

__global__ __launch_bounds__(256, 2) void k_all(const float* __restrict__ x,
                                                const float* __restrict__ Wl,
                                                const float* __restrict__ bl,
                                                const float* __restrict__ Wr,
                                                float* __restrict__ out) {
  // SH: A as float4[64ch][4grp] (4KB) until select done; then W overlay
  // WsL [64][65] @0, WsR @4160 (8320 floats).
  __shared__ float SH[8320];
  float4* Asf4 = (float4*)SH;

  int bi = (int)blockIdx.x, t = threadIdx.x;
  int lane = t & 63, w = t >> 6;
  int n0 = bi << 4;                  // 16 rows/block; batch bounds 16-aligned
  int s = (n0 >= 7168) ? 7168 : (n0 & ~1023);
  const float* xb = x + ((size_t)(s >> 10) << 16);       // batch plane base
  const float* xrow = x + ((size_t)(n0 >> 10) << 16) + (n0 & 1023);

  // stage A: ch = t>>2, grp g = t&3 -> rows n0+4g..n0+4g+3 of channel ch
  {
    int ch = t >> 2, g = t & 3;
    Asf4[t] = *(const float4*)&xrow[((size_t)ch << 10) + (g << 2)];
  }
  __syncthreads();

  // own-rows feature (ch=lane) for transform + singleton; read before overlay
  float4 av = Asf4[(lane << 2) + w];

  float acc[4][16];                  // rows 4w..4w+3 x lane's 16 cols
  float sqa[16];                     // lane's 16 col sq (ascending-ch chain)
#pragma unroll
  for (int r = 0; r < 4; ++r)
#pragma unroll
    for (int j = 0; j < 16; ++j) acc[r][j] = 0.f;
#pragma unroll
  for (int j = 0; j < 16; ++j) sqa[j] = 0.f;

  const float* xl = xb + (lane << 2);

  // ---- GEMM: 2-deep ping-pong, 2 channels per buffer, ascending ch ----
#define LOADB(BUF, CH) do {                                                  \
    const float* xc0_ = xl + ((size_t)(CH) << 10);                           \
    const float* xc1_ = xl + ((size_t)((CH) + 1) << 10);                     \
    BUF[0] = *(const float4*)&xc0_[0];   BUF[1] = *(const float4*)&xc0_[256];\
    BUF[2] = *(const float4*)&xc0_[512]; BUF[3] = *(const float4*)&xc0_[768];\
    BUF[4] = *(const float4*)&xc1_[0];   BUF[5] = *(const float4*)&xc1_[256];\
    BUF[6] = *(const float4*)&xc1_[512]; BUF[7] = *(const float4*)&xc1_[768];\
  } while (0)

#define FMA2(BUF, CH) do {                                                   \
    float4 a0_ = Asf4[((CH) << 2) + w];                                      \
    float4 a1_ = Asf4[(((CH) + 1) << 2) + w];                                \
    float bv0_[16] = {BUF[0].x, BUF[0].y, BUF[0].z, BUF[0].w,                \
                      BUF[1].x, BUF[1].y, BUF[1].z, BUF[1].w,                \
                      BUF[2].x, BUF[2].y, BUF[2].z, BUF[2].w,                \
                      BUF[3].x, BUF[3].y, BUF[3].z, BUF[3].w};               \
    _Pragma("unroll")                                                        \
    for (int j_ = 0; j_ < 16; ++j_) {                                        \
      float bv_ = bv0_[j_];                                                  \
      sqa[j_] = fmaf(bv_, bv_, sqa[j_]);                                     \
      acc[0][j_] = fmaf(a0_.x, bv_, acc[0][j_]);                             \
      acc[1][j_] = fmaf(a0_.y, bv_, acc[1][j_]);                             \
      acc[2][j_] = fmaf(a0_.z, bv_, acc[2][j_]);                             \
      acc[3][j_] = fmaf(a0_.w, bv_, acc[3][j_]);                             \
    }                                                                        \
    float bv1_[16] = {BUF[4].x, BUF[4].y, BUF[4].z, BUF[4].w,                \
                      BUF[5].x, BUF[5].y, BUF[5].z, BUF[5].w,                \
                      BUF[6].x, BUF[6].y, BUF[6].z, BUF[6].w,                \
                      BUF[7].x, BUF[7].y, BUF[7].z, BUF[7].w};               \
    _Pragma("unroll")                                                        \
    for (int j_ = 0; j_ < 16; ++j_) {                                        \
      float bv_ = bv1_[j_];                                                  \
      sqa[j_] = fmaf(bv_, bv_, sqa[j_]);                                     \
      acc[0][j_] = fmaf(a1_.x, bv_, acc[0][j_]);                             \
      acc[1][j_] = fmaf(a1_.y, bv_, acc[1][j_]);                             \
      acc[2][j_] = fmaf(a1_.z, bv_, acc[2][j_]);                             \
      acc[3][j_] = fmaf(a1_.w, bv_, acc[3][j_]);                             \
    }                                                                        \
  } while (0)

  {
    float4 bA[8], bB[8];
    LOADB(bA, 0);
#pragma unroll 1
    for (int g = 0; g < 16; ++g) {
      int c0 = g << 2;
      LOADB(bB, c0 + 2);             // prefetch while FMAing bA
      FMA2(bA, c0);
      if (g < 15) LOADB(bA, c0 + 4); // prefetch while FMAing bB
      FMA2(bB, c0 + 2);
    }
  }

  // ---- selection: keys from registers; 4 rows interleaved ----
#define MKKEY(RR, Q, E, SI, MLAST) ({                                        \
    float dd_ = ((SI) + sqa[((Q) << 2) + (E)]) - 2.f * acc[RR][((Q) << 2) + (E)]; \
    unsigned uu_ = __float_as_uint(dd_);                                     \
    uu_ = (uu_ & 0x80000000u) ? ~uu_ : (uu_ | 0x80000000u);                  \
    u64 kk_ = ((u64)uu_ << 32) | (unsigned)(((Q) << 8) + (lane << 2) + (E)); \
    ((MLAST) && lane == 63 && (Q) == 3 && (E) == 3) ? ~0ull : kk_;           \
  })

  int nrow[4];
  bool sel[4];
  float si4[4];
#pragma unroll
  for (int rr = 0; rr < 4; ++rr) {
    int n = n0 + (w << 2) + rr;
    nrow[rr] = n;
    sel[rr] = (n != 8191);
    int ln = n - s;
    int slot_o = ((ln >> 8) << 2) | (ln & 3);
    float sv = sqa[0];
#pragma unroll
    for (int j = 1; j < 16; ++j) sv = (slot_o == j) ? sqa[j] : sv;
    si4[rr] = __int_as_float(
        __builtin_amdgcn_readlane(__float_as_int(sv), (ln & 255) >> 2));
  }

  u64 m1v[4], m2v[4];
#pragma unroll
  for (int rr = 0; rr < 4; ++rr) {
    bool mlast = (nrow[rr] >= 7168);
    float si = si4[rr];
    u64 m1 = MKKEY(rr, 0, 0, si, mlast);
    u64 m2 = MKKEY(rr, 0, 1, si, mlast);
    if (m2 < m1) { u64 tt = m1; m1 = m2; m2 = tt; }
#pragma unroll
    for (int q = 0; q < 4; ++q)
#pragma unroll
      for (int e = 0; e < 4; ++e) {
        if (q == 0 && e < 2) continue;
        u64 c = MKKEY(rr, q, e, si, mlast);
        u64 lo = (c < m1) ? c : m1;
        u64 hi = (c < m1) ? m1 : c;
        m2 = (hi < m2) ? hi : m2;
        m1 = lo;
      }
    m1v[rr] = m1; m2v[rr] = m2;
  }

#define RESCAN(RR) do {                                                      \
    bool mlast_ = (nrow[RR] >= 7168);                                        \
    float si_ = si4[RR];                                                     \
    u64 best_ = ~0ull;                                                       \
    _Pragma("unroll")                                                        \
    for (int q_ = 0; q_ < 4; ++q_)                                           \
      _Pragma("unroll")                                                      \
      for (int e_ = 0; e_ < 4; ++e_) {                                       \
        u64 c_ = MKKEY(RR, q_, e_, si_, mlast_);                             \
        bool alive_ = ((rmaskv[RR] >> ((q_ << 2) | e_)) & 1u) == 0u;         \
        best_ = (alive_ && c_ < best_) ? c_ : best_;                         \
      }                                                                      \
    lmv[RR] = best_;                                                         \
  } while (0)

#define WINUPD(RR, G) do {                                                   \
    jloc[RR][kk] = (unsigned)(G) & 1023u;                                    \
    if (lmv[RR] == (G)) {                                                    \
      unsigned slot_ = (((unsigned)(G) >> 6) & 12u) | ((unsigned)(G) & 3u);  \
      rmaskv[RR] |= 1u << slot_;                                             \
      if (!stalev[RR]) { lmv[RR] = m2v[RR]; stalev[RR] = true; }             \
      else RESCAN(RR);                                                       \
    }                                                                        \
  } while (0)

  u64 lmv[4] = {m1v[0], m1v[1], m1v[2], m1v[3]};
  unsigned rmaskv[4] = {0u, 0u, 0u, 0u};
  bool stalev[4] = {false, false, false, false};
  unsigned jloc[4][9];
#pragma unroll
  for (int kk = 0; kk < 9; ++kk) {
    u64 g0 = lmv[0], g1 = lmv[1], g2 = lmv[2], g3 = lmv[3];
#pragma unroll
    for (int off = 32; off; off >>= 1) {
      unsigned a0 = __shfl_xor((unsigned)(g0 >> 32), off, 64);
      unsigned b0 = __shfl_xor((unsigned)g0, off, 64);
      unsigned a1 = __shfl_xor((unsigned)(g1 >> 32), off, 64);
      unsigned b1 = __shfl_xor((unsigned)g1, off, 64);
      unsigned a2 = __shfl_xor((unsigned)(g2 >> 32), off, 64);
      unsigned b2 = __shfl_xor((unsigned)g2, off, 64);
      unsigned a3 = __shfl_xor((unsigned)(g3 >> 32), off, 64);
      unsigned b3 = __shfl_xor((unsigned)g3, off, 64);
      u64 o0 = ((u64)a0 << 32) | b0;
      u64 o1 = ((u64)a1 << 32) | b1;
      u64 o2 = ((u64)a2 << 32) | b2;
      u64 o3 = ((u64)a3 << 32) | b3;
      g0 = (o0 < g0) ? o0 : g0;
      g1 = (o1 < g1) ? o1 : g1;
      g2 = (o2 < g2) ? o2 : g2;
      g3 = (o3 < g3) ? o3 : g3;
    }
    WINUPD(0, g0); WINUPD(1, g1); WINUPD(2, g2); WINUPD(3, g3);
  }

  // gathers: 36 independent loads (wave-uniform indices; lane = channel)
  float msum[4];
#pragma unroll
  for (int rr = 0; rr < 4; ++rr) {
    const float* gx = xb + ((size_t)lane << 10);
    float g0 = gx[jloc[rr][0]], g1 = gx[jloc[rr][1]], g2 = gx[jloc[rr][2]];
    float g3 = gx[jloc[rr][3]], g4 = gx[jloc[rr][4]], g5 = gx[jloc[rr][5]];
    float g6 = gx[jloc[rr][6]], g7 = gx[jloc[rr][7]], g8 = gx[jloc[rr][8]];
    msum[rr] = (((g0 + g1) + (g2 + g3)) + ((g4 + g5) + (g6 + g7))) + g8;
  }
  __syncthreads();                   // all A reads done before W overlay

  // stage Ws over dead A: WsL [64][65] @0, WsR @4160
#pragma unroll
  for (int i = 0; i < 16; ++i) {
    int lin = t + (i << 8);
    int o = lin >> 6, c = lin & 63;
    SH[o * 65 + c] = Wl[lin];
    SH[4160 + o * 65 + c] = Wr[lin];
  }
  __syncthreads();

  // transform: lane = output channel; mean-then-linear (= reference order)
  float bias = bl[lane];
  float xr[4] = {av.x, av.y, av.z, av.w};
  float ms[4];
#pragma unroll
  for (int rr = 0; rr < 4; ++rr)
    ms[rr] = sel[rr] ? msum[rr] * (1.f / 9.f) : xr[rr];   // singleton: self
  float accL[4] = {0.f, 0.f, 0.f, 0.f};
  float accR[4] = {0.f, 0.f, 0.f, 0.f};
#pragma unroll
  for (int c = 0; c < 64; ++c) {
    float wlc = SH[lane * 65 + c];
    float wrc = SH[4160 + lane * 65 + c];
#pragma unroll
    for (int rr = 0; rr < 4; ++rr) {
      float mc = __int_as_float(__builtin_amdgcn_readlane(__float_as_int(ms[rr]), c));
      float xc = __int_as_float(__builtin_amdgcn_readlane(__float_as_int(xr[rr]), c));
      accL[rr] = fmaf(mc, wlc, accL[rr]);
      accR[rr] = fmaf(xc, wrc, accR[rr]);
    }
  }
#pragma unroll
  for (int rr = 0; rr < 4; ++rr)
    __builtin_nontemporal_store(accL[rr] + accR[rr] + bias,
                                &out[((size_t)(n0 + (w << 2) + rr) << 6) + lane]);
}

// ---------------------------------------------------------------------------
extern "C" void kernel_launch(void* const* d_in, const int* in_sizes, int n_in,
                              void* d_out, int out_size, void* d_ws, size_t ws_size,
                              hipStream_t stream) {
  const float* x  = (const float*)d_in[0];   // (8,64,32,32)
  const float* Wl = (const float*)d_in[1];   // (64,64)
  const float* bl = (const float*)d_in[2];   // (64,)
  const float* Wr = (const float*)d_in[3];   // (64,64)
  float* out = (float*)d_out;                // (8192,64)
  (void)d_ws; (void)ws_size;                 // workspace unused

  k_all<<<dim3(512), 256, 0, stream>>>(x, Wl, bl, Wr, out);
}